// Round 8
// baseline (265.728 us; speedup 1.0000x reference)
//
#include <hip/hip_runtime.h>
#include <math.h>

// Problem constants
#define NB   8
#define NSEQ 1024
#define CDIM 1024
#define NH   16
#define HD   64
#define TC   3072

typedef unsigned short u16;
typedef __attribute__((ext_vector_type(8))) _Float16 f16x8;
typedef __attribute__((ext_vector_type(4))) float f32x4;

// Workspace layout in u16 units (all fp16):
//   q,k : [B][H][N][D] ; vT : [B][H][D][N]
//   xh  : [8192][1024] (x; later overwritten by o)
//   wqh : [3072][1024] ; owh : [1024][1024]
//   cs  : float2[1024][32] RoPE table (byte offset CS_B)
#define Q_U   ((size_t)0)
#define K_U   ((size_t)8388608)
#define V_U   ((size_t)16777216)
#define XH_U  ((size_t)25165824)
#define WQH_U ((size_t)33554432)
#define OWH_U ((size_t)36700160)
#define CS_B  ((size_t)100663296)

__device__ inline u16 f16b(float f) {
  union { _Float16 h; u16 u; } c;
  c.h = (_Float16)f;
  return c.u;
}
__device__ inline void gload16(const u16* g, u16* l) {
  __builtin_amdgcn_global_load_lds(
      (const __attribute__((address_space(1))) void*)g,
      (__attribute__((address_space(3))) void*)l, 16, 0, 0);
}

// ---------------------------------------------------------------------------
__global__ __launch_bounds__(256) void rope_table_k(float2* __restrict__ cs) {
  int idx = blockIdx.x * 256 + threadIdx.x;
  if (idx >= NSEQ * 32) return;
  int n = idx >> 5, p = idx & 31;
  int t = p >> 1;
  int pos = (p & 1) ? (n & 31) : (n >> 5);
  float th = (float)pow(10000.0, -(double)t / 16.0);
  float ang = (float)pos * th;
  cs[idx] = make_float2(cosf(ang), sinf(ang));
}

// ---------------------------------------------------------------------------
// fp32 -> fp16 convert (RNE), float4-vectorized
__global__ __launch_bounds__(256) void cvt16_k(const float* __restrict__ in,
                                               u16* __restrict__ hi, int n4) {
  int i = blockIdx.x * 256 + threadIdx.x;
  if (i >= n4) return;
  float4 v = ((const float4*)in)[i];
  ushort4 h;
  h.x = f16b(v.x); h.y = f16b(v.y); h.z = f16b(v.z); h.w = f16b(v.w);
  ((ushort4*)hi)[i] = h;
}

// ---------------------------------------------------------------------------
// QKV GEMM, 256x256 tile, 8 waves (2M x 4N), BK=32, ring-4 LDS (128 KB),
// counted vmcnt(8) + ONE raw s_barrier per K-step (T3+T4), setprio (T5),
// bank-swizzled LDS via pre-swizzled global source (T2: blk ^= (row>>1)&3).
// Per wave per step: 12 ds_read_b128 + 32 MFMA (fat phase hides staging).
// Epilogue: bias + RoPE (q,k) fp16 scatter; v stored transposed [bh][d][n].
// ---------------------------------------------------------------------------
__global__ __launch_bounds__(512, 2) void qkv8_k(
    const u16* __restrict__ A, const u16* __restrict__ B,
    const float* __restrict__ bias, u16* __restrict__ q,
    u16* __restrict__ k, u16* __restrict__ v, const float2* __restrict__ cs) {
  // 4 bufs x (A 256x32 + B 256x32) u16 = 4 x 16384 u16 = 128 KB
  __shared__ __align__(16) u16 SM[65536];
  const int K = 1024;

  // XCD-aware bijective swizzle; grid = 12 x 32 = 384 (%8==0), row-major
  // chunks: each XCD runs 4 m-panels x 12 col-tiles -> A panels L2-shared.
  const int bid = blockIdx.y * 12 + blockIdx.x;
  const int swz = (bid & 7) * 48 + (bid >> 3);
  const int bx = swz % 12, by = swz / 12;
  const int m0 = by * 256, c0 = bx * 256;

  const int t = threadIdx.x;
  const int l = t & 63, w = t >> 6;
  const int wr = w >> 2, wcol = w & 3;  // 2M x 4N waves
  const int lr = l & 15, lg = l >> 4;

  // staging: thread t = (row sr = t>>2, blk sb = t&3) of a 128-row half.
  // LDS linear [row][blk] holds global blk (sb ^ swz(row)); swz(r)=(r>>1)&3.
  // swz(r+128)==swz(r), so both halves share the per-thread global offset.
  const int sr = t >> 2;
  const int sgb = (t & 3) ^ ((sr >> 1) & 3);
  const u16* agA = A + (size_t)(m0 + sr) * K + sgb * 8;
  const u16* agB = B + (size_t)(c0 + sr) * K + sgb * 8;
  const size_t rstep = (size_t)128 * K;

  f32x4 acc[8][4] = {};

  auto stage = [&](int kt) {
    u16* base = SM + (kt & 3) * 16384;
    const int ko = kt * 32;
    gload16(agA + ko, base + t * 8);                    // A rows 0-127
    gload16(agA + rstep + ko, base + 4096 + t * 8);     // A rows 128-255
    gload16(agB + ko, base + 8192 + t * 8);             // B rows 0-127
    gload16(agB + rstep + ko, base + 12288 + t * 8);    // B rows 128-255
  };
  auto compute = [&](int kt) {
    const u16* bA = SM + (kt & 3) * 16384;
    const u16* bB = bA + 8192;
    f16x8 bf[4];
#pragma unroll
    for (int ni = 0; ni < 4; ni++) {
      const int R = wcol * 64 + ni * 16 + lr;
      bf[ni] = *(const f16x8*)(bB + R * 32 + ((lg ^ ((R >> 1) & 3)) * 8));
    }
    __builtin_amdgcn_s_setprio(1);
#pragma unroll
    for (int mi = 0; mi < 8; mi++) {
      const int R = wr * 128 + mi * 16 + lr;
      f16x8 af = *(const f16x8*)(bA + R * 32 + ((lg ^ ((R >> 1) & 3)) * 8));
#pragma unroll
      for (int ni = 0; ni < 4; ni++)
        acc[mi][ni] =
            __builtin_amdgcn_mfma_f32_16x16x32_f16(af, bf[ni], acc[mi][ni], 0, 0, 0);
    }
    __builtin_amdgcn_s_setprio(0);
  };

  // prologue: 3 K-tiles in flight (12 loads/wave)
  stage(0);
  stage(1);
  stage(2);

  for (int kt = 0; kt < 32; ++kt) {
    // counted wait: tile kt landed; kt+1,kt+2 stay in flight ACROSS barrier
    if (kt < 30)
      asm volatile("s_waitcnt vmcnt(8)" ::: "memory");
    else if (kt == 30)
      asm volatile("s_waitcnt vmcnt(4)" ::: "memory");
    else
      asm volatile("s_waitcnt vmcnt(0)" ::: "memory");
    __builtin_amdgcn_s_barrier();     // all waves: tile kt ready; buf (kt+3)&3
                                      // (held kt-1) fully consumed
    if (kt < 29) stage(kt + 3);
    compute(kt);
  }

  // epilogue: bias + RoPE + fp16 scatter (no LDS use; no barrier needed)
  const int which = c0 >> 10;  // 0=q 1=k 2=v (256-tiles never cross)
  u16* dst = which == 0 ? q : (which == 1 ? k : v);
  const bool dorope = which < 2;
  const int h = ((c0 & 1023) + wcol * 64) >> 6;  // wave-uniform head
#pragma unroll
  for (int mi = 0; mi < 8; mi++) {
    const int rbase = m0 + wr * 128 + mi * 16 + lg * 4;
#pragma unroll
    for (int ni = 0; ni < 4; ni++) {
      const int d = ni * 16 + lr;
      const float bv = bias[c0 + wcol * 64 + d];
#pragma unroll
      for (int r = 0; r < 4; r++) {
        const int m = rbase + r;
        const int b = m >> 10, n = m & 1023;
        float y = acc[mi][ni][r] + bv;
        if (dorope) {
          float yp = __shfl_xor(y, 1, 64);
          float2 csv = cs[n * 32 + (d >> 1)];
          y = (l & 1) ? fmaf(yp, csv.y, y * csv.x)
                      : fmaf(-yp, csv.y, y * csv.x);
          dst[(((size_t)b * NH + h) * NSEQ + n) * HD + d] = f16b(y);
        } else {
          dst[(((size_t)b * NH + h) * HD + d) * NSEQ + n] = f16b(y);
        }
      }
    }
  }
}

// ---------------------------------------------------------------------------
// out GEMM (round-7 structure, unchanged): 128x128, 4-deep counted vmcnt,
// LDS-transposed coalesced fp32 epilogue.
// ---------------------------------------------------------------------------
__global__ __launch_bounds__(256, 2) void mgemm_k(
    const u16* __restrict__ A, const u16* __restrict__ B,
    const float* __restrict__ bias, float* __restrict__ outF, int K) {
  __shared__ __align__(16) u16 SMEM[32768];

  const int nwg = gridDim.x * gridDim.y;
  const int bid = blockIdx.y * gridDim.x + blockIdx.x;
  const int swz = (bid & 7) * (nwg >> 3) + (bid >> 3);
  const int bx = swz % gridDim.x;
  const int by = swz / gridDim.x;

  const int t = threadIdx.x;
  const int l = t & 63;
  const int w = t >> 6;
  const int wr = w >> 1, wc = w & 1;
  const int lr = l & 15;
  const int lk = (l >> 4) * 8;
  const int m0 = by * 128, c0 = bx * 128;

  const int srow = t >> 2;
  const int skoff = (t & 3) * 8;
  const int soff = srow * 32 + skoff;
  const u16* agA = A + (size_t)(m0 + srow) * K + skoff;
  const u16* agB = B + (size_t)(c0 + srow) * K + skoff;
  const size_t rstep = (size_t)64 * K;

  f32x4 acc[4][4] = {};
  const int NT = K >> 5;

  auto stage = [&](int kt, int s) {
    const int koff = kt << 5;
    u16* dA = SMEM + s * 8192 + soff;
    u16* dB = SMEM + s * 8192 + 4096 + soff;
    gload16(agA + koff, dA);
    gload16(agA + rstep + koff, dA + 2048);
    gload16(agB + koff, dB);
    gload16(agB + rstep + koff, dB + 2048);
  };
  auto compute = [&](int s) {
    const u16* cA = SMEM + s * 8192;
    const u16* cB = cA + 4096;
    f16x8 bfr[4];
#pragma unroll
    for (int ni = 0; ni < 4; ni++)
      bfr[ni] = *(const f16x8*)(cB + (wc * 64 + ni * 16 + lr) * 32 + lk);
#pragma unroll
    for (int mi = 0; mi < 4; mi++) {
      f16x8 a = *(const f16x8*)(cA + (wr * 64 + mi * 16 + lr) * 32 + lk);
#pragma unroll
      for (int ni = 0; ni < 4; ni++)
        acc[mi][ni] =
            __builtin_amdgcn_mfma_f32_16x16x32_f16(a, bfr[ni], acc[mi][ni], 0, 0, 0);
    }
  };

  stage(0, 0);
  stage(1, 1);
  stage(2, 2);

  for (int kt = 0; kt < NT - 2; ++kt) {
    asm volatile("s_waitcnt vmcnt(8)" ::: "memory");
    __builtin_amdgcn_s_barrier();
    if (kt + 3 < NT) stage(kt + 3, (kt + 3) & 3);
    compute(kt & 3);
  }
  asm volatile("s_waitcnt vmcnt(4)" ::: "memory");
  __builtin_amdgcn_s_barrier();
  compute((NT - 2) & 3);
  asm volatile("s_waitcnt vmcnt(0)" ::: "memory");
  __builtin_amdgcn_s_barrier();
  compute((NT - 1) & 3);

  float* fl = (float*)SMEM;
#pragma unroll
  for (int mi = 0; mi < 4; mi++) {
    __syncthreads();
#pragma unroll
    for (int ni = 0; ni < 4; ni++)
#pragma unroll
      for (int r = 0; r < 4; r++)
        fl[(wr * 16 + (l >> 4) * 4 + r) * 132 + wc * 64 + ni * 16 + lr] =
            acc[mi][ni][r];
    __syncthreads();
#pragma unroll
    for (int p = 0; p < 4; p++) {
      const int sr = (t >> 5) + p * 8;
      const int sc = (t & 31) * 4;
      float4 vv = *(float4*)&fl[sr * 132 + sc];
      float4 bv = *(const float4*)&bias[c0 + sc];
      vv.x += bv.x; vv.y += bv.y; vv.z += bv.z; vv.w += bv.w;
      const int grow = m0 + (sr >> 4) * 64 + mi * 16 + (sr & 15);
      *(float4*)&outF[(size_t)grow * CDIM + c0 + sc] = vv;
    }
  }
}

// ---------------------------------------------------------------------------
// MFMA flash attention, all-fp16 operands (unchanged from round 5/6/7).
// ---------------------------------------------------------------------------
__global__ __launch_bounds__(256) void attn_k(const u16* __restrict__ qg0,
                                              const u16* __restrict__ kg0,
                                              const u16* __restrict__ vtg0,
                                              u16* __restrict__ og) {
  __shared__ __align__(16) u16 Ks[4096];     // 64 keys x 64 d (swizzled)
  __shared__ __align__(16) u16 Vt[4096];     // 64 d x 64 keys (swizzled)
  __shared__ __align__(16) u16 Ps[4][1024];  // per-wave 16 q x 64 keys (swz)
  const int t = threadIdx.x;
  const int l = t & 63, w = t >> 6;
  const int lr = l & 15, lg = l >> 4;
  const int bh = blockIdx.x;
  const int n0 = blockIdx.y * 64;

  f16x8 qf[2];
  {
    const u16* qp = qg0 + ((size_t)bh * NSEQ + n0 + w * 16 + lr) * HD + lg * 8;
#pragma unroll
    for (int c = 0; c < 2; c++) {
      f16x8 raw = *(const f16x8*)(qp + c * 32);
#pragma unroll
      for (int j = 0; j < 8; j++) raw[j] = raw[j] * (_Float16)0.125f;
      qf[c] = raw;
    }
  }

  const int r0 = t >> 3, b0 = (t & 7) ^ (r0 & 7);
  const int r1 = (256 + t) >> 3, b1 = ((256 + t) & 7) ^ (r1 & 7);
  const u16* kgb = kg0 + (size_t)bh * NSEQ * HD;
  const u16* vgb = vtg0 + (size_t)bh * HD * NSEQ;
  const u16* kga0 = kgb + r0 * 64 + b0 * 8;
  const u16* kga1 = kgb + r1 * 64 + b1 * 8;
  const u16* vga0 = vgb + r0 * 1024 + b0 * 8;
  const u16* vga1 = vgb + r1 * 1024 + b1 * 8;
  u16* ksd0 = Ks + (size_t)t * 8;
  u16* ksd1 = Ks + (size_t)(256 + t) * 8;
  u16* vtd0 = Vt + (size_t)t * 8;
  u16* vtd1 = Vt + (size_t)(256 + t) * 8;

  float m_run[4], l_run[4];
  f32x4 oa[4] = {};
#pragma unroll
  for (int r = 0; r < 4; r++) { m_run[r] = -INFINITY; l_run[r] = 0.f; }

  for (int kt = 0; kt < 16; kt++) {
    __syncthreads();
    gload16(kga0 + kt * 4096, ksd0);
    gload16(kga1 + kt * 4096, ksd1);
    gload16(vga0 + kt * 64, vtd0);
    gload16(vga1 + kt * 64, vtd1);
    __syncthreads();

    f32x4 s[4] = {};
#pragma unroll
    for (int c = 0; c < 2; c++) {
#pragma unroll
      for (int ni = 0; ni < 4; ni++) {
        const int kr = ni * 16 + lr;
        f16x8 kf = *(const f16x8*)&Ks[kr * 64 + (((c * 4 + lg) ^ (kr & 7)) * 8)];
        s[ni] = __builtin_amdgcn_mfma_f32_16x16x32_f16(qf[c], kf, s[ni], 0, 0, 0);
      }
    }

    float tm[4];
#pragma unroll
    for (int r = 0; r < 4; r++) {
      float m1 = fmaxf(fmaxf(s[0][r], s[1][r]), fmaxf(s[2][r], s[3][r]));
      m1 = fmaxf(m1, __shfl_xor(m1, 1, 64));
      m1 = fmaxf(m1, __shfl_xor(m1, 2, 64));
      m1 = fmaxf(m1, __shfl_xor(m1, 4, 64));
      m1 = fmaxf(m1, __shfl_xor(m1, 8, 64));
      tm[r] = m1;
    }
    const bool ok = (tm[0] <= m_run[0] + 8.f) && (tm[1] <= m_run[1] + 8.f) &&
                    (tm[2] <= m_run[2] + 8.f) && (tm[3] <= m_run[3] + 8.f);
    if (!__all(ok)) {
#pragma unroll
      for (int r = 0; r < 4; r++) {
        const float mn = fmaxf(m_run[r], tm[r]);
        const float fs = __expf(m_run[r] - mn);
        m_run[r] = mn;
        l_run[r] *= fs;
#pragma unroll
        for (int ni = 0; ni < 4; ni++) oa[ni][r] *= fs;
      }
    }
#pragma unroll
    for (int r = 0; r < 4; r++) {
      float p[4], ps = 0.f;
#pragma unroll
      for (int ni = 0; ni < 4; ni++) { p[ni] = __expf(s[ni][r] - m_run[r]); ps += p[ni]; }
      l_run[r] += ps;
      const int prow = lg * 4 + r;
      const int sw = prow & 7;
#pragma unroll
      for (int ni = 0; ni < 4; ni++)
        Ps[w][prow * 64 + (((ni * 2 + (lr >> 3)) ^ sw) * 8) + (lr & 7)] =
            f16b(p[ni]);
    }

#pragma unroll
    for (int c = 0; c < 2; c++) {
      f16x8 pa = *(const f16x8*)&Ps[w][lr * 64 + (((c * 4 + lg) ^ (lr & 7)) * 8)];
#pragma unroll
      for (int ni = 0; ni < 4; ni++) {
        const int dr = ni * 16 + lr;
        f16x8 vf = *(const f16x8*)&Vt[dr * 64 + (((c * 4 + lg) ^ (dr & 7)) * 8)];
        oa[ni] = __builtin_amdgcn_mfma_f32_16x16x32_f16(pa, vf, oa[ni], 0, 0, 0);
      }
    }
  }

  const int b = bh >> 4, h = bh & 15;
#pragma unroll
  for (int r = 0; r < 4; r++) {
    float lv = l_run[r];
    lv += __shfl_xor(lv, 1, 64);
    lv += __shfl_xor(lv, 2, 64);
    lv += __shfl_xor(lv, 4, 64);
    lv += __shfl_xor(lv, 8, 64);
    const float inv = 1.0f / lv;
    const size_t n = n0 + w * 16 + lg * 4 + r;
    const size_t base = ((size_t)b * NSEQ + n) * CDIM + h * HD;
#pragma unroll
    for (int ni = 0; ni < 4; ni++)
      og[base + ni * 16 + lr] = f16b(oa[ni][r] * inv);
  }
}

// ---------------------------------------------------------------------------
extern "C" void kernel_launch(void* const* d_in, const int* in_sizes, int n_in,
                              void* d_out, int out_size, void* d_ws, size_t ws_size,
                              hipStream_t stream) {
  const float* x      = (const float*)d_in[0];
  const float* wqkv_w = (const float*)d_in[1];
  const float* wqkv_b = (const float*)d_in[2];
  const float* out_w  = (const float*)d_in[3];
  const float* out_b  = (const float*)d_in[4];
  float* out = (float*)d_out;
  u16* ws = (u16*)d_ws;
  float2* cs = (float2*)((char*)d_ws + CS_B);

  rope_table_k<<<dim3((NSEQ * 32 + 255) / 256), 256, 0, stream>>>(cs);
  cvt16_k<<<dim3(8192), 256, 0, stream>>>(x, ws + XH_U, 2097152);
  cvt16_k<<<dim3(3072), 256, 0, stream>>>(wqkv_w, ws + WQH_U, 786432);
  cvt16_k<<<dim3(1024), 256, 0, stream>>>(out_w, ws + OWH_U, 262144);

  // QKV GEMM: 256x256 8-wave counted-vmcnt pipeline + RoPE epilogue
  qkv8_k<<<dim3(TC / 256, (NB * NSEQ) / 256), 512, 0, stream>>>(
      ws + XH_U, ws + WQH_U, wqkv_b, ws + Q_U, ws + K_U, ws + V_U, cs);

  // flash attention (fp16 MFMA) -> o fp16 (overwrites x region)
  attn_k<<<dim3(NB * NH, NSEQ / 64), 256, 0, stream>>>(
      ws + Q_U, ws + K_U, ws + V_U, ws + XH_U);

  // out GEMM (fp16, 4-deep counted-vmcnt) + bias -> fp32 d_out (coalesced)
  mgemm_k<<<dim3(CDIM / 128, (NB * NSEQ) / 128), 256, 0, stream>>>(
      ws + XH_U, ws + OWH_U, out_b, out, CDIM);
}